// Round 3
// baseline (1658.831 us; speedup 1.0000x reference)
//
#include <hip/hip_runtime.h>
#include <math.h>

#define Bg 8
#define Nn 256
#define Ee 65536
#define Dd 512
#define LNEPS 1e-5f

static __device__ __forceinline__ float wave_sum(float v) {
#pragma unroll
  for (int off = 32; off; off >>= 1) v += __shfl_xor(v, off);
  return v;
}
static __device__ __forceinline__ float wave_max(float v) {
#pragma unroll
  for (int off = 32; off; off >>= 1) v = fmaxf(v, __shfl_xor(v, off));
  return v;
}

// ---------------- row LayerNorm: one wave per 512-elem row ----------------
__global__ __launch_bounds__(256) void ln_kernel(
    const float* __restrict__ X, const float* __restrict__ gam,
    const float* __restrict__ bet, float* __restrict__ Y)
{
  const int lane = threadIdx.x & 63, wv = threadIdx.x >> 6;
  const int row = blockIdx.x * 4 + wv;
  const float4* x4 = (const float4*)(X + (size_t)row * Dd);
  float4 a = x4[lane * 2 + 0], b = x4[lane * 2 + 1];
  float s = a.x + a.y + a.z + a.w + b.x + b.y + b.z + b.w;
  s = wave_sum(s);
  const float mu = s * (1.0f / Dd);
  a.x -= mu; a.y -= mu; a.z -= mu; a.w -= mu;
  b.x -= mu; b.y -= mu; b.z -= mu; b.w -= mu;
  float v = a.x * a.x + a.y * a.y + a.z * a.z + a.w * a.w
          + b.x * b.x + b.y * b.y + b.z * b.z + b.w * b.w;
  v = wave_sum(v);
  const float rs = 1.0f / sqrtf(v * (1.0f / Dd) + LNEPS);
  const float4* g4 = (const float4*)gam + lane * 2;
  const float4* c4 = (const float4*)bet + lane * 2;
  float4 g0 = g4[0], g1 = g4[1], c0 = c4[0], c1 = c4[1];
  float4 y0, y1;
  y0.x = a.x * rs * g0.x + c0.x; y0.y = a.y * rs * g0.y + c0.y;
  y0.z = a.z * rs * g0.z + c0.z; y0.w = a.w * rs * g0.w + c0.w;
  y1.x = b.x * rs * g1.x + c1.x; y1.y = b.y * rs * g1.y + c1.y;
  y1.z = b.z * rs * g1.z + c1.z; y1.w = b.w * rs * g1.w + c1.w;
  float4* y4 = (float4*)(Y + (size_t)row * Dd);
  y4[lane * 2 + 0] = y0; y4[lane * 2 + 1] = y1;
}

#define MMA16() do { \
  acc[0][0] = fmaf(av.x, wv.x, acc[0][0]); \
  acc[0][1] = fmaf(av.x, wv.y, acc[0][1]); \
  acc[0][2] = fmaf(av.x, wv.z, acc[0][2]); \
  acc[0][3] = fmaf(av.x, wv.w, acc[0][3]); \
  acc[1][0] = fmaf(av.y, wv.x, acc[1][0]); \
  acc[1][1] = fmaf(av.y, wv.y, acc[1][1]); \
  acc[1][2] = fmaf(av.y, wv.z, acc[1][2]); \
  acc[1][3] = fmaf(av.y, wv.w, acc[1][3]); \
  acc[2][0] = fmaf(av.z, wv.x, acc[2][0]); \
  acc[2][1] = fmaf(av.z, wv.y, acc[2][1]); \
  acc[2][2] = fmaf(av.z, wv.z, acc[2][2]); \
  acc[2][3] = fmaf(av.z, wv.w, acc[2][3]); \
  acc[3][0] = fmaf(av.w, wv.x, acc[3][0]); \
  acc[3][1] = fmaf(av.w, wv.y, acc[3][1]); \
  acc[3][2] = fmaf(av.w, wv.z, acc[3][2]); \
  acc[3][3] = fmaf(av.w, wv.w, acc[3][3]); \
} while (0)

// C[M,N] = epi( A[M,K] @ W[N,K]^T ).  EPI: 0=+bias, 1=(+bias)*colscale,
// 2=relu(+bias), 3=relu(+bias+addm)
template<int EPI>
__global__ __launch_bounds__(256) void gemm_nt(
    const float* __restrict__ A, const float* __restrict__ W,
    const float* __restrict__ bias, const float* __restrict__ cs,
    const float* __restrict__ addm, float* __restrict__ C,
    int M, int N, int K)
{
  __shared__ float As[16][68];
  __shared__ float Ws[16][68];
  const int tid = threadIdx.x;
  const int bm = blockIdx.y * 64, bn = blockIdx.x * 64;
  const int lr = tid >> 2, lk = (tid & 3) << 2;          // loader
  const int cr = (tid >> 4) << 2, cc = (tid & 15) << 2;  // compute
  float acc[4][4] = {};
  const float* Ap = A + (size_t)(bm + lr) * K + lk;
  const float* Wp = W + (size_t)(bn + lr) * K + lk;
  for (int k0 = 0; k0 < K; k0 += 16) {
    const float4 a = *(const float4*)(Ap + k0);
    const float4 w = *(const float4*)(Wp + k0);
    __syncthreads();
    As[lk + 0][lr] = a.x; As[lk + 1][lr] = a.y;
    As[lk + 2][lr] = a.z; As[lk + 3][lr] = a.w;
    Ws[lk + 0][lr] = w.x; Ws[lk + 1][lr] = w.y;
    Ws[lk + 2][lr] = w.z; Ws[lk + 3][lr] = w.w;
    __syncthreads();
#pragma unroll
    for (int kk = 0; kk < 16; ++kk) {
      const float4 av = *(const float4*)&As[kk][cr];
      const float4 wv = *(const float4*)&Ws[kk][cc];
      MMA16();
    }
  }
  const int c = bn + cc;
  const float4 bs = *(const float4*)(bias + c);
  float4 csv = {1.f, 1.f, 1.f, 1.f};
  if (EPI == 1) csv = *(const float4*)(cs + c);
#pragma unroll
  for (int i = 0; i < 4; ++i) {
    const int r = bm + cr + i;
    float4 o;
    o.x = acc[i][0] + bs.x; o.y = acc[i][1] + bs.y;
    o.z = acc[i][2] + bs.z; o.w = acc[i][3] + bs.w;
    if (EPI == 1) { o.x *= csv.x; o.y *= csv.y; o.z *= csv.z; o.w *= csv.w; }
    if (EPI == 3) {
      const float4 ad = *(const float4*)(addm + (size_t)r * N + c);
      o.x += ad.x; o.y += ad.y; o.z += ad.z; o.w += ad.w;
    }
    if (EPI >= 2) {
      o.x = fmaxf(o.x, 0.f); o.y = fmaxf(o.y, 0.f);
      o.z = fmaxf(o.z, 0.f); o.w = fmaxf(o.w, 0.f);
    }
    *(float4*)(C + (size_t)r * N + c) = o;
  }
}

// ---- atten_f: one wave per edge-iteration; streams union rows (HBM-bound) ----
__global__ __launch_bounds__(256) void atten_kernel(
    const float* __restrict__ sp, const float* __restrict__ op,
    const float* __restrict__ phr, const int* __restrict__ pairs,
    const float* __restrict__ wbp, float* __restrict__ att)
{
  const int lane = threadIdx.x & 63, wv = threadIdx.x >> 6;
  const float wb = *wbp;
  const long base = ((long)blockIdx.x * 4 + wv) * 16;
  for (int t = 0; t < 16; ++t) {
    const long idx = base + t;
    const int g = (int)(idx >> 16);          // E = 65536
    const int e = (int)(idx & (Ee - 1));
    const int2 pr = *(const int2*)(pairs + ((size_t)g * Ee + e) * 2);
    const float4* u4 = (const float4*)(phr + ((size_t)g * Ee + e) * Dd) + lane * 2;
    const float4* s4 = (const float4*)(sp + ((size_t)g * Nn + pr.x) * Dd) + lane * 2;
    const float4* o4 = (const float4*)(op + ((size_t)g * Nn + pr.y) * Dd) + lane * 2;
    const float4 u0 = u4[0], u1 = u4[1];
    const float4 s0 = s4[0], s1 = s4[1];
    const float4 o0 = o4[0], o1 = o4[1];
    float acc = s0.x * o0.x * u0.x + s0.y * o0.y * u0.y
              + s0.z * o0.z * u0.z + s0.w * o0.w * u0.w
              + s1.x * o1.x * u1.x + s1.y * o1.y * u1.y
              + s1.z * o1.z * u1.z + s1.w * o1.w * u1.w;
    acc = wave_sum(acc);
    if (lane == 0)
      atomicAdd(att + ((size_t)g * Nn + pr.x) * Nn + pr.y, acc + wb);
  }
}

// ---- diag -10000 + row softmax, in place; one wave per 256-elem row ----
__global__ __launch_bounds__(256) void softmax_kernel(float* __restrict__ att)
{
  const int lane = threadIdx.x & 63, wv = threadIdx.x >> 6;
  const int row = blockIdx.x * 4 + wv;     // 0..B*N-1
  const int r = row & (Nn - 1);
  float* p = att + (size_t)row * Nn;
  float4 x = ((float4*)p)[lane];
  if ((r >> 2) == lane) ((float*)&x)[r & 3] -= 10000.0f;
  float mx = fmaxf(fmaxf(x.x, x.y), fmaxf(x.z, x.w));
  mx = wave_max(mx);
  x.x = expf(x.x - mx); x.y = expf(x.y - mx);
  x.z = expf(x.z - mx); x.w = expf(x.w - mx);
  float s = x.x + x.y + x.z + x.w;
  s = wave_sum(s);
  const float inv = 1.0f / s;
  x.x *= inv; x.y *= inv; x.z *= inv; x.w *= inv;
  ((float4*)p)[lane] = x;
}

// ---- ctx = att @ v (NN), writes ctx to d_out and out = obj + ctx to scratch ----
__global__ __launch_bounds__(256) void ctx_gemm(
    const float* __restrict__ att, const float* __restrict__ V,
    const float* __restrict__ obj, float* __restrict__ ctx,
    float* __restrict__ outb)
{
  __shared__ float As[16][68];
  __shared__ float Bs[16][68];
  const int g = blockIdx.z;
  const int tid = threadIdx.x;
  const int bm = blockIdx.y * 64, bn = blockIdx.x * 64;
  const int lr = tid >> 2, lk = (tid & 3) << 2;          // A loader (transpose)
  const int kr = tid >> 4, cn = (tid & 15) << 2;         // B loader (direct)
  const int cr = (tid >> 4) << 2, cc = (tid & 15) << 2;
  const float* Ag = att + (size_t)g * Nn * Nn;
  const float* Vg = V + (size_t)g * Nn * Dd;
  float acc[4][4] = {};
  for (int k0 = 0; k0 < Nn; k0 += 16) {
    const float4 a = *(const float4*)(Ag + (size_t)(bm + lr) * Nn + k0 + lk);
    const float4 b = *(const float4*)(Vg + (size_t)(k0 + kr) * Dd + bn + cn);
    __syncthreads();
    As[lk + 0][lr] = a.x; As[lk + 1][lr] = a.y;
    As[lk + 2][lr] = a.z; As[lk + 3][lr] = a.w;
    *(float4*)&Bs[kr][cn] = b;
    __syncthreads();
#pragma unroll
    for (int kk = 0; kk < 16; ++kk) {
      const float4 av = *(const float4*)&As[kk][cr];
      const float4 wv = *(const float4*)&Bs[kk][cc];
      MMA16();
    }
  }
#pragma unroll
  for (int i = 0; i < 4; ++i) {
    const size_t off = ((size_t)g * Nn + bm + cr + i) * Dd + bn + cc;
    float4 o;
    o.x = acc[i][0]; o.y = acc[i][1]; o.z = acc[i][2]; o.w = acc[i][3];
    *(float4*)(ctx + off) = o;
    const float4 ob = *(const float4*)(obj + off);
    o.x += ob.x; o.y += ob.y; o.z += ob.z; o.w += ob.w;
    *(float4*)(outb + off) = o;
  }
}

extern "C" void kernel_launch(void* const* d_in, const int* in_sizes, int n_in,
                              void* d_out, int out_size, void* d_ws, size_t ws_size,
                              hipStream_t stream) {
  const float* obj    = (const float*)d_in[0];
  const float* phr    = (const float*)d_in[1];
  const int*   pairs  = (const int*)d_in[2];
  const float* ws_w   = (const float*)d_in[3];
  const float* ws_b   = (const float*)d_in[4];
  const float* wo_w   = (const float*)d_in[5];
  const float* wo_b   = (const float*)d_in[6];
  const float* w_w    = (const float*)d_in[7];
  const float* w_b    = (const float*)d_in[8];
  const float* conv_w = (const float*)d_in[9];
  const float* conv_b = (const float*)d_in[10];
  const float* ln1_g  = (const float*)d_in[11];
  const float* ln1_b  = (const float*)d_in[12];
  const float* ln2_g  = (const float*)d_in[13];
  const float* ln2_b  = (const float*)d_in[14];
  const float* t1_w   = (const float*)d_in[15];
  const float* t1_b   = (const float*)d_in[16];
  const float* t2_w   = (const float*)d_in[17];
  const float* t2_b   = (const float*)d_in[18];

  float* outp    = (float*)d_out;
  float* refined = outp;                                   // B*N*D
  float* att     = outp + (size_t)Bg * Nn * Dd;            // B*N*N
  float* ctx     = att + (size_t)Bg * Nn * Nn;             // B*N*D

  float* ws   = (float*)d_ws;
  float* sbuf = ws;                 // [0, 1M)  s' = (obj@ws^T+b)*w
  float* obuf = ws + 1048576;       // [1M, 2M) o
  float* vbuf = ws + 2097152;       // [2M, 3M) v
  float* outb = ws + 3145728;       // [3M, 4M) out = obj + ctx
  float* lnb  = ws + 4194304;       // [4M, 5M) ln1 then h (LN2 out)
  float* ubuf = ws;                 // reuse [0, 2M) after atten for u (2048x1024)

  const int M = Bg * Nn;  // 2048

  hipMemsetAsync(att, 0, (size_t)Bg * Nn * Nn * sizeof(float), stream);
  ln_kernel<<<512, 256, 0, stream>>>(obj, ln1_g, ln1_b, lnb);
  gemm_nt<1><<<dim3(8, 32), 256, 0, stream>>>(obj, ws_w, ws_b, w_w, nullptr, sbuf, M, 512, 512);
  gemm_nt<0><<<dim3(8, 32), 256, 0, stream>>>(obj, wo_w, wo_b, nullptr, nullptr, obuf, M, 512, 512);
  gemm_nt<2><<<dim3(8, 32), 256, 0, stream>>>(lnb, conv_w, conv_b, nullptr, nullptr, vbuf, M, 512, 512);
  atten_kernel<<<8192, 256, 0, stream>>>(sbuf, obuf, phr, pairs, w_b, att);
  softmax_kernel<<<512, 256, 0, stream>>>(att);
  ctx_gemm<<<dim3(8, 4, 8), 256, 0, stream>>>(att, vbuf, obj, ctx, outb);
  ln_kernel<<<512, 256, 0, stream>>>(outb, ln2_g, ln2_b, lnb);
  gemm_nt<2><<<dim3(16, 32), 256, 0, stream>>>(lnb, t1_w, t1_b, nullptr, nullptr, ubuf, M, 1024, 512);
  gemm_nt<3><<<dim3(8, 32), 256, 0, stream>>>(ubuf, t2_w, t2_b, nullptr, outb, refined, M, 512, 1024);
}